// Round 6
// baseline (389.485 us; speedup 1.0000x reference)
//
#include <hip/hip_runtime.h>
#include <hip/hip_bf16.h>

// Problem constants (Head_24799141167224)
// Inputs fp32, output fp32 (compared at bf16 precision, 2% rel).
// ws cap: 10,137,856 B proven (R4 fault at 11.2 MB). d_out = scratch until attn.
// R10 lesson: bulk atomicAdd split-K accumulation = ~32 B HBM RMW per scalar.
// R11 lesson: removing barriers/LDS alone didn't help (93 us invariant).
// R12 lesson: 4-deep A prefetch regressed (ILP not the limiter).
// R13 lesson: launch_bounds(512,4) forced VGPR=64 -> full spill (120 us).
// R14 lesson: circular-phase K loop refuted the channel-alias theory
//   (neutral-to-worse: 104.8 us, FETCH +5 MB from broken B locality). Reverted.
// R15: the one clean un-tested axis is TLP. All rounds ran 2 waves/SIMD.
//   N-split waves (rg x nh) halve per-wave state -> 1024 blocks, 4 blocks/CU,
//   4 waves/SIMD, no spills. Same v5 QSTEP codegen, ni=4.
#define NB 4
#define NT 4096
#define NC 2048
#define ND 128
#define NK 409      // int(0.1 * 4096)
#define KPAD 416
#define NM (NB * NK)   // 1636

typedef __attribute__((ext_vector_type(8))) short short8;   // 8 bf16
typedef __attribute__((ext_vector_type(4))) float f32x4;

union S8U { short8 v; ushort u[8]; };

// RNE split: x = hi + lo (both bf16), |x - hi - lo| <= ~2^-18 |x|
__device__ __forceinline__ void split2(float x, ushort& h, ushort& l) {
    union { float f; unsigned u; } a; a.f = x;
    unsigned r = a.u + 0x7FFFu + ((a.u >> 16) & 1u);
    h = (ushort)(r >> 16);
    union { unsigned u; float f; } hb; hb.u = ((unsigned)h) << 16;
    float res = x - hb.f;
    union { float f; unsigned u; } b; b.f = res;
    unsigned r2 = b.u + 0x7FFFu + ((b.u >> 16) & 1u);
    l = (ushort)(r2 >> 16);
}

__device__ __forceinline__ uint4 pack8(const ushort* s) {
    uint4 v;
    v.x = (unsigned)s[0] | ((unsigned)s[1] << 16);
    v.y = (unsigned)s[2] | ((unsigned)s[3] << 16);
    v.z = (unsigned)s[4] | ((unsigned)s[5] << 16);
    v.w = (unsigned)s[6] | ((unsigned)s[7] << 16);
    return v;
}

// B tile-major slot (layout produced by bconv_tiles). Fragments stay
// 16B-contiguous; a wave's 64 fragment loads for one ni span 1 KB.
__device__ __forceinline__ int slotOf(int n, int lq) {
    return n * 4 + ((lq + (n >> 1)) & 3);
}

// ---------------------------------------------------------------------------
// Kernel 0: W [2048][128] fp32 -> Bt tile-major bf16 hi/lo:
// Bt[kt][part][slot][8 ushorts], kt=k/32, slot=slotOf(n,lq), elems k=lq*8+j.
// 1 MB per weight matrix. One block per kt.
// ---------------------------------------------------------------------------
__global__ __launch_bounds__(256) void bconv_tiles(
    const float* __restrict__ W, ushort* __restrict__ Bt)
{
    const int kt = blockIdx.x;       // 0..63
    const int t = threadIdx.x;
    const int n = t & 127;
    const int lq0 = (t >> 7) * 2;    // 0 or 2
    #pragma unroll
    for (int e = 0; e < 2; ++e) {
        int lq = lq0 + e;
        ushort h[8], l[8];
        #pragma unroll
        for (int j = 0; j < 8; ++j) {
            float x = W[(size_t)(kt * 32 + lq * 8 + j) * ND + n];  // coalesced
            split2(x, h[j], l[j]);
        }
        int slot = slotOf(n, lq);
        *(uint4*)&Bt[((size_t)(kt * 2 + 0) * 512 + slot) * 8] = pack8(h);
        *(uint4*)&Bt[((size_t)(kt * 2 + 1) * 512 + slot) * 8] = pack8(l);
    }
}

// ---------------------------------------------------------------------------
// Shared GEMM step (v5 codegen, ni=4): 2-deep B register double buffer,
// 1-deep A prefetch, 12 MFMAs. Barrier-free; per-wave 16x64 strip.
// ---------------------------------------------------------------------------
#define QSTEP(BHC, BLC, BHN, BLN, KT)                                         \
    {                                                                         \
        short8 ah, al;                                                        \
        {                                                                     \
            S8U H, L;                                                         \
            float xs[8] = {fa0.x, fa0.y, fa0.z, fa0.w,                        \
                           fa1.x, fa1.y, fa1.z, fa1.w};                       \
            _Pragma("unroll")                                                 \
            for (int j = 0; j < 8; ++j) split2(xs[j], H.u[j], L.u[j]);        \
            ah = H.v; al = L.v;                                               \
        }                                                                     \
        const int ktn = ((KT) + 1 < KITER) ? (KT) + 1 : (KT);                 \
        const ushort* gbn = Bt + (size_t)(kt0 + ktn) * 8192;                  \
        _Pragma("unroll")                                                     \
        for (int ni = 0; ni < 4; ++ni) {                                      \
            BHN[ni] = *(const short8*)(gbn + boff[ni]);                       \
            BLN[ni] = *(const short8*)(gbn + 4096 + boff[ni]);                \
        }                                                                     \
        fa0 = *(const float4*)(arow + ktn * 32);                              \
        fa1 = *(const float4*)(arow + ktn * 32 + 4);                          \
        _Pragma("unroll")                                                     \
        for (int ni = 0; ni < 4; ++ni) {                                      \
            acc[ni] = __builtin_amdgcn_mfma_f32_16x16x32_bf16(ah, BHC[ni], acc[ni], 0, 0, 0); \
            acc[ni] = __builtin_amdgcn_mfma_f32_16x16x32_bf16(ah, BLC[ni], acc[ni], 0, 0, 0); \
            acc[ni] = __builtin_amdgcn_mfma_f32_16x16x32_bf16(al, BHC[ni], acc[ni], 0, 0, 0); \
        }                                                                     \
    }

// ---------------------------------------------------------------------------
// Kernel 1: q = index @ Wq. R15: wave = 16 rows x 64 cols (rg = w&1,
// nh = w>>1), M-tile 32. Grid (512, QSPLIT=2) = 1024 blocks = 4 blocks/CU
// = 16 waves/CU = 4 waves/SIMD (2x all previous rounds). ~80-100 VGPR,
// no cap, no spill. Partials q1/q2 non-atomic.
// ---------------------------------------------------------------------------
#define QSPLIT 2
__global__ __launch_bounds__(256) void qgemm_v9(
    const float* __restrict__ A, const ushort* __restrict__ Bt,
    float* __restrict__ q1, float* __restrict__ q2)
{
    const int tid = threadIdx.x;
    const int w = tid >> 6, lane = tid & 63;
    const int rg = w & 1, nh = w >> 1;
    const int lrow = lane & 15, lq = lane >> 4;
    const int m0 = blockIdx.x * 32;
    const int KITER = (NC / QSPLIT) / 32;                 // 32
    const int kt0 = blockIdx.y * KITER;
    const int kb = blockIdx.y * (NC / QSPLIT);

    const float* arow = A + (size_t)(m0 + rg * 16 + lrow) * NC + kb + lq * 8;

    int boff[4];
    #pragma unroll
    for (int ni = 0; ni < 4; ++ni)
        boff[ni] = slotOf(nh * 64 + ni * 16 + lrow, lq) * 8;

    f32x4 acc[4];
    #pragma unroll
    for (int i = 0; i < 4; ++i) acc[i] = (f32x4){0.f, 0.f, 0.f, 0.f};

    // prologue: B(0) into set A, A(0) into fa
    short8 bhA[4], blA[4], bhB[4], blB[4];
    {
        const ushort* gb = Bt + (size_t)kt0 * 8192;   // 2*512*8 ushorts per kt
        #pragma unroll
        for (int ni = 0; ni < 4; ++ni) {
            bhA[ni] = *(const short8*)(gb + boff[ni]);
            blA[ni] = *(const short8*)(gb + 4096 + boff[ni]);
        }
    }
    float4 fa0 = *(const float4*)(arow + 0);
    float4 fa1 = *(const float4*)(arow + 4);

    for (int kt = 0; kt < KITER; kt += 2) {
        QSTEP(bhA, blA, bhB, blB, kt);
        QSTEP(bhB, blB, bhA, blA, kt + 1);
    }

    float* __restrict__ qd = blockIdx.y ? q2 : q1;
    // C/D layout: col = lane&15 (lrow), row = lq*4 + r
    #pragma unroll
    for (int ni = 0; ni < 4; ++ni) {
        const int col = nh * 64 + ni * 16 + lrow;
        #pragma unroll
        for (int r = 0; r < 4; ++r) {
            const int grow = m0 + rg * 16 + lq * 4 + r;
            qd[(size_t)grow * ND + col] = acc[ni][r];
        }
    }
}

// ---------------------------------------------------------------------------
// Kernel 1b: gathered K/V projection — same wave split. M-tile 32,
// grid (52, KVSPLIT=8, 2) = 832 blocks = 3.3 blocks/CU. Small atomic
// epilogue (~3.4M atomics ~ 109 MB RMW — tolerated).
// ---------------------------------------------------------------------------
#define KVSPLIT 8
__global__ __launch_bounds__(256) void kvgemm_v9(
    const float* __restrict__ X, const ushort* __restrict__ Bkt,
    const ushort* __restrict__ Bvt, const int* __restrict__ topi,
    float* __restrict__ ktop, float* __restrict__ vtop)
{
    const int tid = threadIdx.x;
    const int w = tid >> 6, lane = tid & 63;
    const int rg = w & 1, nh = w >> 1;
    const int lrow = lane & 15, lq = lane >> 4;
    const int m0 = blockIdx.x * 32;
    const int KITER = (NC / KVSPLIT) / 32;                // 8
    const int kt0 = blockIdx.y * KITER;
    const int kb = blockIdx.y * (NC / KVSPLIT);
    const ushort* __restrict__ Bt = blockIdx.z ? Bvt : Bkt;

    const int gi = m0 + rg * 16 + lrow;
    const int giC = gi < NM ? gi : NM - 1;
    const int b = giC / NK, ii = giC % NK;
    const int src = topi[b * KPAD + ii];
    const float* arow = X + ((size_t)b * NT + src) * NC + kb + lq * 8;

    int boff[4];
    #pragma unroll
    for (int ni = 0; ni < 4; ++ni)
        boff[ni] = slotOf(nh * 64 + ni * 16 + lrow, lq) * 8;

    f32x4 acc[4];
    #pragma unroll
    for (int i = 0; i < 4; ++i) acc[i] = (f32x4){0.f, 0.f, 0.f, 0.f};

    short8 bhA[4], blA[4], bhB[4], blB[4];
    {
        const ushort* gb = Bt + (size_t)kt0 * 8192;
        #pragma unroll
        for (int ni = 0; ni < 4; ++ni) {
            bhA[ni] = *(const short8*)(gb + boff[ni]);
            blA[ni] = *(const short8*)(gb + 4096 + boff[ni]);
        }
    }
    float4 fa0 = *(const float4*)(arow + 0);
    float4 fa1 = *(const float4*)(arow + 4);

    for (int kt = 0; kt < KITER; kt += 2) {
        QSTEP(bhA, blA, bhB, blB, kt);
        QSTEP(bhB, blB, bhA, blA, kt + 1);
    }

    float* __restrict__ dst = blockIdx.z ? vtop : ktop;
    #pragma unroll
    for (int ni = 0; ni < 4; ++ni) {
        const int col = nh * 64 + ni * 16 + lrow;
        #pragma unroll
        for (int r = 0; r < 4; ++r) {
            const int grow = m0 + rg * 16 + lq * 4 + r;
            if (grow < NM)
                atomicAdd(&dst[(size_t)grow * ND + col], acc[ni][r]);
        }
    }
}

// ---------------------------------------------------------------------------
// Kernel 2: q = q1 + q2 (in-place into q1) + q_norms. One wave per row.
// ---------------------------------------------------------------------------
__global__ __launch_bounds__(256) void qnorm_kernel(
    float* __restrict__ q1, const float* __restrict__ q2, float* __restrict__ qn)
{
    const int wv = (blockIdx.x * 256 + threadIdx.x) >> 6;
    const int lane = threadIdx.x & 63;
    float* r1 = q1 + (size_t)wv * ND;
    const float* r2 = q2 + (size_t)wv * ND;
    float a = r1[lane] + r2[lane];
    float b = r1[lane + 64] + r2[lane + 64];
    r1[lane] = a;
    r1[lane + 64] = b;
    float s = a * a + b * b;
    #pragma unroll
    for (int off = 32; off > 0; off >>= 1) s += __shfl_xor(s, off);
    if (lane == 0) qn[wv] = sqrtf(s);
}

// ---------------------------------------------------------------------------
// Kernel 3: exact top-k by rank counting (jax.lax.top_k tie rules).
// ---------------------------------------------------------------------------
__global__ __launch_bounds__(256) void topk_kernel(
    const float* __restrict__ qn, int* __restrict__ topi, int* __restrict__ cnt)
{
    __shared__ int rs[4][64];
    const int b = blockIdx.y;
    const int is = threadIdx.x & 63;
    const int i = blockIdx.x * 64 + is;
    const int chunk = threadIdx.x >> 6;
    const float vi = qn[(size_t)b * NT + i];
    const float4* qv = (const float4*)(qn + (size_t)b * NT + chunk * 1024);
    int rank = 0;
    #pragma unroll 4
    for (int j4 = 0; j4 < 256; ++j4) {
        float4 v = qv[j4];
        int j = chunk * 1024 + j4 * 4;
        rank += (v.x > vi || (v.x == vi && (j + 0) < i)) ? 1 : 0;
        rank += (v.y > vi || (v.y == vi && (j + 1) < i)) ? 1 : 0;
        rank += (v.z > vi || (v.z == vi && (j + 2) < i)) ? 1 : 0;
        rank += (v.w > vi || (v.w == vi && (j + 3) < i)) ? 1 : 0;
    }
    rs[chunk][is] = rank;
    __syncthreads();
    if (threadIdx.x < 64) {
        int rk = rs[0][threadIdx.x] + rs[1][threadIdx.x] + rs[2][threadIdx.x] + rs[3][threadIdx.x];
        if (rk < NK) {
            int p = atomicAdd(&cnt[b], 1);
            topi[b * KPAD + p] = blockIdx.x * 64 + threadIdx.x;
        }
    }
}

// ---------------------------------------------------------------------------
// Kernel 5: per (batch, top-k row): scores -> softmax -> PV -> scatter.
// ---------------------------------------------------------------------------
__global__ __launch_bounds__(256) void attn_kernel(
    const float* __restrict__ q, const float* __restrict__ ktop,
    const float* __restrict__ vtop, const int* __restrict__ topi,
    float* __restrict__ out)
{
    __shared__ float qs[ND];
    __shared__ float ss[KPAD];
    __shared__ float red[256];
    __shared__ float pv[2][ND];
    const int bi = blockIdx.x;
    const int b = bi / NK, i = bi % NK;
    const int t = threadIdx.x;
    const int row = topi[b * KPAD + i];
    if (t < ND) qs[t] = q[((size_t)b * NT + row) * ND + t];
    __syncthreads();

    const float scale = 0.08838834764831844f;   // 1/sqrt(128)
    float mymax = -1e30f;
    #pragma unroll
    for (int rep = 0; rep < 2; ++rep) {
        int j = t + rep * 256;
        if (j < NK) {
            const float4* kr = (const float4*)(ktop + ((size_t)b * NK + j) * ND);
            const float4* q4 = (const float4*)qs;
            float s = 0.f;
            #pragma unroll
            for (int dd = 0; dd < 32; ++dd) {
                float4 a = q4[dd], kv = kr[dd];
                s += a.x * kv.x + a.y * kv.y + a.z * kv.z + a.w * kv.w;
            }
            s *= scale;
            ss[j] = s;
            mymax = fmaxf(mymax, s);
        }
    }
    red[t] = mymax;
    __syncthreads();
    for (int off = 128; off > 0; off >>= 1) {
        if (t < off) red[t] = fmaxf(red[t], red[t + off]);
        __syncthreads();
    }
    const float mx = red[0];
    __syncthreads();

    float mysum = 0.f;
    #pragma unroll
    for (int rep = 0; rep < 2; ++rep) {
        int j = t + rep * 256;
        if (j < NK) {
            float p = __expf(ss[j] - mx);
            ss[j] = p;
            mysum += p;
        }
    }
    red[t] = mysum;
    __syncthreads();
    for (int off = 128; off > 0; off >>= 1) {
        if (t < off) red[t] += red[t + off];
        __syncthreads();
    }
    const float inv = 1.f / red[0];

    const int col = t & (ND - 1), half = t >> 7;
    float o = 0.f;
    #pragma unroll 4
    for (int j = half; j < NK; j += 2)
        o = fmaf(ss[j], vtop[((size_t)b * NK + j) * ND + col], o);
    pv[half][col] = o;
    __syncthreads();
    if (t < ND)
        out[((size_t)b * NT + row) * ND + t] = (pv[0][t] + pv[1][t]) * inv;
}

// ---------------------------------------------------------------------------
extern "C" void kernel_launch(void* const* d_in, const int* in_sizes, int n_in,
                              void* d_out, int out_size, void* d_ws, size_t ws_size,
                              hipStream_t stream)
{
    const float* index = (const float*)d_in[0];
    const float* Wq = (const float*)d_in[1];
    const float* Wk = (const float*)d_in[2];
    const float* Wv = (const float*)d_in[3];
    float* out = (float*)d_out;

    // ws: 10,137,856 B proven footprint.
    char* ws = (char*)d_ws;
    float*  q1   = (float*)(ws);                       // 8,388,608
    float*  qn   = (float*)(ws + 8388608);             //    65,536
    int*    topi = (int*)  (ws + 8454144);             //     8,192
    int*    cnt  = (int*)  (ws + 8462336);             //       256
    ushort* Bqt  = (ushort*)(ws + 8462592);            // 1,048,576 (phase 1)
    float*  ktop = (float*)(ws + 8462592);             //   837,632 (phase 2)
    float*  vtop = (float*)(ws + 9300224);             //   837,632 (phase 2)

    // d_out scratch: q2 partial (phase A), then Bkt/Bvt (phase B), then output.
    float*  q2  = (float*)d_out;
    ushort* Bkt = (ushort*)d_out;                      // 1,048,576
    ushort* Bvt = (ushort*)((char*)d_out + 1048576);   // 1,048,576

    hipMemsetAsync(cnt, 0, NB * sizeof(int), stream);

    bconv_tiles<<<dim3(64), dim3(256), 0, stream>>>(Wq, Bqt);
    qgemm_v9<<<dim3(NB * NT / 32, QSPLIT), dim3(256), 0, stream>>>(index, Bqt, q1, q2);
    qnorm_kernel<<<dim3(NB * NT / 4), dim3(256), 0, stream>>>(q1, q2, qn);
    topk_kernel<<<dim3(NT / 64, NB), dim3(256), 0, stream>>>(qn, topi, cnt);
    bconv_tiles<<<dim3(64), dim3(256), 0, stream>>>(Wk, Bkt);
    bconv_tiles<<<dim3(64), dim3(256), 0, stream>>>(Wv, Bvt);
    hipMemsetAsync(ktop, 0, 2 * 837632, stream);   // zero ktop+vtop (atomic accum)
    kvgemm_v9<<<dim3((NM + 31) / 32, KVSPLIT, 2), dim3(256), 0, stream>>>(
        index, Bkt, Bvt, topi, ktop, vtop);
    hipMemsetAsync(d_out, 0, (size_t)out_size * sizeof(float), stream);
    attn_kernel<<<dim3(NM), dim3(256), 0, stream>>>(q1, ktop, vtop, topi, out);
}

// Round 7
// 377.251 us; speedup vs baseline: 1.0324x; 1.0324x over previous
//
#include <hip/hip_runtime.h>
#include <hip/hip_bf16.h>

// Problem constants (Head_24799141167224)
// Inputs fp32, output fp32 (compared at bf16 precision, 2% rel).
// ws cap: 10,137,856 B proven (R4 fault at 11.2 MB). d_out = scratch until attn.
// R10 lesson: bulk atomicAdd split-K accumulation = ~32 B HBM RMW per scalar.
// R11 lesson: removing barriers/LDS alone didn't help (93 us invariant).
// R12 lesson: 4-deep A prefetch (1-step-apart issue) regressed.
// R13 lesson: launch_bounds(512,4) forced VGPR=64 -> full spill (120 us).
// R14 lesson: K-phase decorrelation refuted channel-alias theory (neutral).
// R15 lesson: 4 waves/SIMD (Occ 24%, no spill) neutral-to-worse -> TLP
//   exonerated. All axes (barriers, ILP, phase, TLP, atomics) = 90-108 us.
// R16 theory: A stream is DRAM-page-activate-bound: each row visited in
//   128 B granules ~7000 cycles apart -> 1 activate per 128 B -> ~1.4 TB/s
//   effective (= 134 MB / 93 us exactly). Fix: group K-steps by 4, burst
//   8 A-load instrs back-to-back -> 512 B/row page-coherent clumps.
#define NB 4
#define NT 4096
#define NC 2048
#define ND 128
#define NK 409      // int(0.1 * 4096)
#define KPAD 416
#define NM (NB * NK)   // 1636

typedef __attribute__((ext_vector_type(8))) short short8;   // 8 bf16
typedef __attribute__((ext_vector_type(4))) float f32x4;

union S8U { short8 v; ushort u[8]; };

// RNE split: x = hi + lo (both bf16), |x - hi - lo| <= ~2^-18 |x|
__device__ __forceinline__ void split2(float x, ushort& h, ushort& l) {
    union { float f; unsigned u; } a; a.f = x;
    unsigned r = a.u + 0x7FFFu + ((a.u >> 16) & 1u);
    h = (ushort)(r >> 16);
    union { unsigned u; float f; } hb; hb.u = ((unsigned)h) << 16;
    float res = x - hb.f;
    union { float f; unsigned u; } b; b.f = res;
    unsigned r2 = b.u + 0x7FFFu + ((b.u >> 16) & 1u);
    l = (ushort)(r2 >> 16);
}

__device__ __forceinline__ uint4 pack8(const ushort* s) {
    uint4 v;
    v.x = (unsigned)s[0] | ((unsigned)s[1] << 16);
    v.y = (unsigned)s[2] | ((unsigned)s[3] << 16);
    v.z = (unsigned)s[4] | ((unsigned)s[5] << 16);
    v.w = (unsigned)s[6] | ((unsigned)s[7] << 16);
    return v;
}

// B tile-major slot (layout produced by bconv_tiles). Fragments stay
// 16B-contiguous; a wave's 64 fragment loads for one ni span 1 KB.
__device__ __forceinline__ int slotOf(int n, int lq) {
    return n * 4 + ((lq + (n >> 1)) & 3);
}

// ---------------------------------------------------------------------------
// Kernel 0: W [2048][128] fp32 -> Bt tile-major bf16 hi/lo:
// Bt[kt][part][slot][8 ushorts], kt=k/32, slot=slotOf(n,lq), elems k=lq*8+j.
// 1 MB per weight matrix. One block per kt.
// ---------------------------------------------------------------------------
__global__ __launch_bounds__(256) void bconv_tiles(
    const float* __restrict__ W, ushort* __restrict__ Bt)
{
    const int kt = blockIdx.x;       // 0..63
    const int t = threadIdx.x;
    const int n = t & 127;
    const int lq0 = (t >> 7) * 2;    // 0 or 2
    #pragma unroll
    for (int e = 0; e < 2; ++e) {
        int lq = lq0 + e;
        ushort h[8], l[8];
        #pragma unroll
        for (int j = 0; j < 8; ++j) {
            float x = W[(size_t)(kt * 32 + lq * 8 + j) * ND + n];  // coalesced
            split2(x, h[j], l[j]);
        }
        int slot = slotOf(n, lq);
        *(uint4*)&Bt[((size_t)(kt * 2 + 0) * 512 + slot) * 8] = pack8(h);
        *(uint4*)&Bt[((size_t)(kt * 2 + 1) * 512 + slot) * 8] = pack8(l);
    }
}

// ---------------------------------------------------------------------------
// GEMM step (v5 codegen, A-load removed): split2 current fragment, prefetch
// next B tile (2-deep register dbuf), 24 MFMAs. Barrier-free; wave=16x128.
// ---------------------------------------------------------------------------
#define QSTEP(BHC, BLC, BHN, BLN, KTN, F0, F1)                                \
    {                                                                         \
        short8 ah, al;                                                        \
        {                                                                     \
            S8U H, L;                                                         \
            float xs[8] = {F0.x, F0.y, F0.z, F0.w,                            \
                           F1.x, F1.y, F1.z, F1.w};                           \
            _Pragma("unroll")                                                 \
            for (int j = 0; j < 8; ++j) split2(xs[j], H.u[j], L.u[j]);        \
            ah = H.v; al = L.v;                                               \
        }                                                                     \
        const ushort* gbn = Bt + (size_t)(kt0 + (KTN)) * 8192;                \
        _Pragma("unroll")                                                     \
        for (int ni = 0; ni < 8; ++ni) {                                      \
            BHN[ni] = *(const short8*)(gbn + boff[ni]);                       \
            BLN[ni] = *(const short8*)(gbn + 4096 + boff[ni]);                \
        }                                                                     \
        _Pragma("unroll")                                                     \
        for (int ni = 0; ni < 8; ++ni) {                                      \
            acc[ni] = __builtin_amdgcn_mfma_f32_16x16x32_bf16(ah, BHC[ni], acc[ni], 0, 0, 0); \
            acc[ni] = __builtin_amdgcn_mfma_f32_16x16x32_bf16(ah, BLC[ni], acc[ni], 0, 0, 0); \
            acc[ni] = __builtin_amdgcn_mfma_f32_16x16x32_bf16(al, BHC[ni], acc[ni], 0, 0, 0); \
        }                                                                     \
    }

// A group burst: 8 back-to-back loads = 16 rows x 512 B contiguous (4 K-steps).
// Same addresses/registers as v5's per-step fa pairs; only issue timing differs.
#define ABURST(FB, KT4)                                                       \
    _Pragma("unroll")                                                         \
    for (int s = 0; s < 4; ++s) {                                             \
        FB[s][0] = *(const float4*)(arow + ((KT4) + s) * 32);                 \
        FB[s][1] = *(const float4*)(arow + ((KT4) + s) * 32 + 4);             \
    }

// ---------------------------------------------------------------------------
// Kernel 1: q = index @ Wq. v5 structure (wave=16x128, M-tile 64, grid
// (256, QSPLIT=2)=512 blocks) + R16 group-of-4 A bursts, group-level
// double buffer faA/faB (~+48 VGPR -> ~160-180, >=2 waves/SIMD, no cap).
// Partials q1/q2 non-atomic.
// ---------------------------------------------------------------------------
#define QSPLIT 2
__global__ __launch_bounds__(256) void qgemm_v10(
    const float* __restrict__ A, const ushort* __restrict__ Bt,
    float* __restrict__ q1, float* __restrict__ q2)
{
    const int tid = threadIdx.x;
    const int w = tid >> 6, lane = tid & 63;
    const int lrow = lane & 15, lq = lane >> 4;
    const int m0 = blockIdx.x * 64;
    const int KITER = (NC / QSPLIT) / 32;                 // 32
    const int kt0 = blockIdx.y * KITER;
    const int kb = blockIdx.y * (NC / QSPLIT);

    const float* arow = A + (size_t)(m0 + w * 16 + lrow) * NC + kb + lq * 8;

    int boff[8];
    #pragma unroll
    for (int ni = 0; ni < 8; ++ni)
        boff[ni] = slotOf(ni * 16 + lrow, lq) * 8;

    f32x4 acc[8];
    #pragma unroll
    for (int i = 0; i < 8; ++i) acc[i] = (f32x4){0.f, 0.f, 0.f, 0.f};

    // prologue: B(0) into set A; A group 0 burst into faA
    short8 bhA[8], blA[8], bhB[8], blB[8];
    {
        const ushort* gb = Bt + (size_t)kt0 * 8192;   // 2*512*8 ushorts per kt
        #pragma unroll
        for (int ni = 0; ni < 8; ++ni) {
            bhA[ni] = *(const short8*)(gb + boff[ni]);
            blA[ni] = *(const short8*)(gb + 4096 + boff[ni]);
        }
    }
    float4 faA[4][2], faB[4][2];
    ABURST(faA, 0);

    for (int g = 0; g < 8; g += 2) {
        ABURST(faB, g * 4 + 4);                       // max 28: covers kt 28..31
        QSTEP(bhA, blA, bhB, blB, g * 4 + 1, faA[0][0], faA[0][1]);
        QSTEP(bhB, blB, bhA, blA, g * 4 + 2, faA[1][0], faA[1][1]);
        QSTEP(bhA, blA, bhB, blB, g * 4 + 3, faA[2][0], faA[2][1]);
        QSTEP(bhB, blB, bhA, blA, g * 4 + 4, faA[3][0], faA[3][1]);
        if (g + 2 < 8) { ABURST(faA, g * 4 + 8); }    // skip past-end group
        QSTEP(bhA, blA, bhB, blB, g * 4 + 5, faB[0][0], faB[0][1]);
        QSTEP(bhB, blB, bhA, blA, g * 4 + 6, faB[1][0], faB[1][1]);
        QSTEP(bhA, blA, bhB, blB, g * 4 + 7, faB[2][0], faB[2][1]);
        QSTEP(bhB, blB, bhA, blA, (g * 4 + 8 < 32 ? g * 4 + 8 : 31),
              faB[3][0], faB[3][1]);                  // tail reloads t31 (ok)
    }

    float* __restrict__ qd = blockIdx.y ? q2 : q1;
    // C/D layout: col = lane&15 (lrow), row = lq*4 + r
    #pragma unroll
    for (int ni = 0; ni < 8; ++ni) {
        const int col = ni * 16 + lrow;
        #pragma unroll
        for (int r = 0; r < 4; ++r) {
            const int grow = m0 + w * 16 + lq * 4 + r;
            qd[(size_t)grow * ND + col] = acc[ni][r];
        }
    }
}

// ---------------------------------------------------------------------------
// Kernel 1b: gathered K/V projection. v5 wave strip (M-tile 64, ni=8) +
// full prologue A burst: KITER=8 -> both groups (1 KB/row contiguous)
// issued upfront. grid (26, KVSPLIT=8, 2) = 416 blocks; small atomic
// epilogue (~3.4M atomics — tolerated).
// ---------------------------------------------------------------------------
#define KVSPLIT 8
__global__ __launch_bounds__(256) void kvgemm_v10(
    const float* __restrict__ X, const ushort* __restrict__ Bkt,
    const ushort* __restrict__ Bvt, const int* __restrict__ topi,
    float* __restrict__ ktop, float* __restrict__ vtop)
{
    const int tid = threadIdx.x;
    const int w = tid >> 6, lane = tid & 63;
    const int lrow = lane & 15, lq = lane >> 4;
    const int m0 = blockIdx.x * 64;
    const int KITER = (NC / KVSPLIT) / 32;                // 8
    const int kt0 = blockIdx.y * KITER;
    const int kb = blockIdx.y * (NC / KVSPLIT);
    const ushort* __restrict__ Bt = blockIdx.z ? Bvt : Bkt;

    const int gi = m0 + w * 16 + lrow;
    const int giC = gi < NM ? gi : NM - 1;
    const int b = giC / NK, ii = giC % NK;
    const int src = topi[b * KPAD + ii];
    const float* arow = X + ((size_t)b * NT + src) * NC + kb + lq * 8;

    int boff[8];
    #pragma unroll
    for (int ni = 0; ni < 8; ++ni)
        boff[ni] = slotOf(ni * 16 + lrow, lq) * 8;

    f32x4 acc[8];
    #pragma unroll
    for (int i = 0; i < 8; ++i) acc[i] = (f32x4){0.f, 0.f, 0.f, 0.f};

    short8 bhA[8], blA[8], bhB[8], blB[8];
    {
        const ushort* gb = Bt + (size_t)kt0 * 8192;
        #pragma unroll
        for (int ni = 0; ni < 8; ++ni) {
            bhA[ni] = *(const short8*)(gb + boff[ni]);
            blA[ni] = *(const short8*)(gb + 4096 + boff[ni]);
        }
    }
    float4 faA[4][2], faB[4][2];
    ABURST(faA, 0);
    ABURST(faB, 4);    // whole row-slice (1 KB/row) in flight, page-coherent

    QSTEP(bhA, blA, bhB, blB, 1, faA[0][0], faA[0][1]);
    QSTEP(bhB, blB, bhA, blA, 2, faA[1][0], faA[1][1]);
    QSTEP(bhA, blA, bhB, blB, 3, faA[2][0], faA[2][1]);
    QSTEP(bhB, blB, bhA, blA, 4, faA[3][0], faA[3][1]);
    QSTEP(bhA, blA, bhB, blB, 5, faB[0][0], faB[0][1]);
    QSTEP(bhB, blB, bhA, blA, 6, faB[1][0], faB[1][1]);
    QSTEP(bhA, blA, bhB, blB, 7, faB[2][0], faB[2][1]);
    QSTEP(bhB, blB, bhA, blA, 7, faB[3][0], faB[3][1]);   // tail reload (ok)

    float* __restrict__ dst = blockIdx.z ? vtop : ktop;
    #pragma unroll
    for (int ni = 0; ni < 8; ++ni) {
        const int col = ni * 16 + lrow;
        #pragma unroll
        for (int r = 0; r < 4; ++r) {
            const int grow = m0 + w * 16 + lq * 4 + r;
            if (grow < NM)
                atomicAdd(&dst[(size_t)grow * ND + col], acc[ni][r]);
        }
    }
}

// ---------------------------------------------------------------------------
// Kernel 2: q = q1 + q2 (in-place into q1) + q_norms. One wave per row.
// ---------------------------------------------------------------------------
__global__ __launch_bounds__(256) void qnorm_kernel(
    float* __restrict__ q1, const float* __restrict__ q2, float* __restrict__ qn)
{
    const int wv = (blockIdx.x * 256 + threadIdx.x) >> 6;
    const int lane = threadIdx.x & 63;
    float* r1 = q1 + (size_t)wv * ND;
    const float* r2 = q2 + (size_t)wv * ND;
    float a = r1[lane] + r2[lane];
    float b = r1[lane + 64] + r2[lane + 64];
    r1[lane] = a;
    r1[lane + 64] = b;
    float s = a * a + b * b;
    #pragma unroll
    for (int off = 32; off > 0; off >>= 1) s += __shfl_xor(s, off);
    if (lane == 0) qn[wv] = sqrtf(s);
}

// ---------------------------------------------------------------------------
// Kernel 3: exact top-k by rank counting (jax.lax.top_k tie rules).
// ---------------------------------------------------------------------------
__global__ __launch_bounds__(256) void topk_kernel(
    const float* __restrict__ qn, int* __restrict__ topi, int* __restrict__ cnt)
{
    __shared__ int rs[4][64];
    const int b = blockIdx.y;
    const int is = threadIdx.x & 63;
    const int i = blockIdx.x * 64 + is;
    const int chunk = threadIdx.x >> 6;
    const float vi = qn[(size_t)b * NT + i];
    const float4* qv = (const float4*)(qn + (size_t)b * NT + chunk * 1024);
    int rank = 0;
    #pragma unroll 4
    for (int j4 = 0; j4 < 256; ++j4) {
        float4 v = qv[j4];
        int j = chunk * 1024 + j4 * 4;
        rank += (v.x > vi || (v.x == vi && (j + 0) < i)) ? 1 : 0;
        rank += (v.y > vi || (v.y == vi && (j + 1) < i)) ? 1 : 0;
        rank += (v.z > vi || (v.z == vi && (j + 2) < i)) ? 1 : 0;
        rank += (v.w > vi || (v.w == vi && (j + 3) < i)) ? 1 : 0;
    }
    rs[chunk][is] = rank;
    __syncthreads();
    if (threadIdx.x < 64) {
        int rk = rs[0][threadIdx.x] + rs[1][threadIdx.x] + rs[2][threadIdx.x] + rs[3][threadIdx.x];
        if (rk < NK) {
            int p = atomicAdd(&cnt[b], 1);
            topi[b * KPAD + p] = blockIdx.x * 64 + threadIdx.x;
        }
    }
}

// ---------------------------------------------------------------------------
// Kernel 5: per (batch, top-k row): scores -> softmax -> PV -> scatter.
// ---------------------------------------------------------------------------
__global__ __launch_bounds__(256) void attn_kernel(
    const float* __restrict__ q, const float* __restrict__ ktop,
    const float* __restrict__ vtop, const int* __restrict__ topi,
    float* __restrict__ out)
{
    __shared__ float qs[ND];
    __shared__ float ss[KPAD];
    __shared__ float red[256];
    __shared__ float pv[2][ND];
    const int bi = blockIdx.x;
    const int b = bi / NK, i = bi % NK;
    const int t = threadIdx.x;
    const int row = topi[b * KPAD + i];
    if (t < ND) qs[t] = q[((size_t)b * NT + row) * ND + t];
    __syncthreads();

    const float scale = 0.08838834764831844f;   // 1/sqrt(128)
    float mymax = -1e30f;
    #pragma unroll
    for (int rep = 0; rep < 2; ++rep) {
        int j = t + rep * 256;
        if (j < NK) {
            const float4* kr = (const float4*)(ktop + ((size_t)b * NK + j) * ND);
            const float4* q4 = (const float4*)qs;
            float s = 0.f;
            #pragma unroll
            for (int dd = 0; dd < 32; ++dd) {
                float4 a = q4[dd], kv = kr[dd];
                s += a.x * kv.x + a.y * kv.y + a.z * kv.z + a.w * kv.w;
            }
            s *= scale;
            ss[j] = s;
            mymax = fmaxf(mymax, s);
        }
    }
    red[t] = mymax;
    __syncthreads();
    for (int off = 128; off > 0; off >>= 1) {
        if (t < off) red[t] = fmaxf(red[t], red[t + off]);
        __syncthreads();
    }
    const float mx = red[0];
    __syncthreads();

    float mysum = 0.f;
    #pragma unroll
    for (int rep = 0; rep < 2; ++rep) {
        int j = t + rep * 256;
        if (j < NK) {
            float p = __expf(ss[j] - mx);
            ss[j] = p;
            mysum += p;
        }
    }
    red[t] = mysum;
    __syncthreads();
    for (int off = 128; off > 0; off >>= 1) {
        if (t < off) red[t] += red[t + off];
        __syncthreads();
    }
    const float inv = 1.f / red[0];

    const int col = t & (ND - 1), half = t >> 7;
    float o = 0.f;
    #pragma unroll 4
    for (int j = half; j < NK; j += 2)
        o = fmaf(ss[j], vtop[((size_t)b * NK + j) * ND + col], o);
    pv[half][col] = o;
    __syncthreads();
    if (t < ND)
        out[((size_t)b * NT + row) * ND + t] = (pv[0][t] + pv[1][t]) * inv;
}

// ---------------------------------------------------------------------------
extern "C" void kernel_launch(void* const* d_in, const int* in_sizes, int n_in,
                              void* d_out, int out_size, void* d_ws, size_t ws_size,
                              hipStream_t stream)
{
    const float* index = (const float*)d_in[0];
    const float* Wq = (const float*)d_in[1];
    const float* Wk = (const float*)d_in[2];
    const float* Wv = (const float*)d_in[3];
    float* out = (float*)d_out;

    // ws: 10,137,856 B proven footprint.
    char* ws = (char*)d_ws;
    float*  q1   = (float*)(ws);                       // 8,388,608
    float*  qn   = (float*)(ws + 8388608);             //    65,536
    int*    topi = (int*)  (ws + 8454144);             //     8,192
    int*    cnt  = (int*)  (ws + 8462336);             //       256
    ushort* Bqt  = (ushort*)(ws + 8462592);            // 1,048,576 (phase 1)
    float*  ktop = (float*)(ws + 8462592);             //   837,632 (phase 2)
    float*  vtop = (float*)(ws + 9300224);             //   837,632 (phase 2)

    // d_out scratch: q2 partial (phase A), then Bkt/Bvt (phase B), then output.
    float*  q2  = (float*)d_out;
    ushort* Bkt = (ushort*)d_out;                      // 1,048,576
    ushort* Bvt = (ushort*)((char*)d_out + 1048576);   // 1,048,576

    hipMemsetAsync(cnt, 0, NB * sizeof(int), stream);

    bconv_tiles<<<dim3(64), dim3(256), 0, stream>>>(Wq, Bqt);
    qgemm_v10<<<dim3(NB * NT / 64, QSPLIT), dim3(256), 0, stream>>>(index, Bqt, q1, q2);
    qnorm_kernel<<<dim3(NB * NT / 4), dim3(256), 0, stream>>>(q1, q2, qn);
    topk_kernel<<<dim3(NT / 64, NB), dim3(256), 0, stream>>>(qn, topi, cnt);
    bconv_tiles<<<dim3(64), dim3(256), 0, stream>>>(Wk, Bkt);
    bconv_tiles<<<dim3(64), dim3(256), 0, stream>>>(Wv, Bvt);
    hipMemsetAsync(ktop, 0, 2 * 837632, stream);   // zero ktop+vtop (atomic accum)
    kvgemm_v10<<<dim3((NM + 63) / 64, KVSPLIT, 2), dim3(256), 0, stream>>>(
        index, Bkt, Bvt, topi, ktop, vtop);
    hipMemsetAsync(d_out, 0, (size_t)out_size * sizeof(float), stream);
    attn_kernel<<<dim3(NM), dim3(256), 0, stream>>>(q1, ktop, vtop, topi, out);
}

// Round 8
// 369.700 us; speedup vs baseline: 1.0535x; 1.0204x over previous
//
#include <hip/hip_runtime.h>
#include <hip/hip_bf16.h>

// Problem constants (Head_24799141167224)
// Inputs fp32, output fp32 (compared at bf16 precision, 2% rel).
// ws cap: 10,137,856 B proven (R4 fault at 11.2 MB). d_out = scratch until attn.
// R10 lesson: bulk atomicAdd split-K accumulation = ~32 B HBM RMW per scalar.
// R11 lesson: removing barriers/LDS alone didn't help (93 us invariant).
// R12 lesson: 4-deep A prefetch (1-step-apart issue) regressed.
// R13 lesson: launch_bounds(512,4) forced VGPR=64 -> full spill (120 us).
// R14 lesson: K-phase decorrelation refuted channel-alias theory (neutral).
// R15 lesson: 4 waves/SIMD neutral -> TLP exonerated.
// R16 lesson: 512B page-coherent A bursts perfectly neutral (93.5 us,
//   counters identical to R2) -> DRAM-page theory dead. Per-CU byte volume
//   DIFFERS 3x between R0 and R2 at identical time -> L1/L2 BW exonerated.
// R17 theory: every variant issues A AFTER the 16 B-loads; the next step's
//   split2 consumes A = youngest outstanding VMEM; in-order vmcnt retire
//   [m135] forces vmcnt(0) FULL DRAIN every K-step (R0's syncthreads ditto).
//   ~2-3k cycle exposed round-trip x 2 correlated waves = the ~7k cyc/step
//   invariant. Fix: issue A BEFORE B -> split2 waits vmcnt(16), MFMA waits
//   vmcnt(18); queue never empties.
#define NB 4
#define NT 4096
#define NC 2048
#define ND 128
#define NK 409      // int(0.1 * 4096)
#define KPAD 416
#define NM (NB * NK)   // 1636

typedef __attribute__((ext_vector_type(8))) short short8;   // 8 bf16
typedef __attribute__((ext_vector_type(4))) float f32x4;

union S8U { short8 v; ushort u[8]; };

// RNE split: x = hi + lo (both bf16), |x - hi - lo| <= ~2^-18 |x|
__device__ __forceinline__ void split2(float x, ushort& h, ushort& l) {
    union { float f; unsigned u; } a; a.f = x;
    unsigned r = a.u + 0x7FFFu + ((a.u >> 16) & 1u);
    h = (ushort)(r >> 16);
    union { unsigned u; float f; } hb; hb.u = ((unsigned)h) << 16;
    float res = x - hb.f;
    union { float f; unsigned u; } b; b.f = res;
    unsigned r2 = b.u + 0x7FFFu + ((b.u >> 16) & 1u);
    l = (ushort)(r2 >> 16);
}

__device__ __forceinline__ uint4 pack8(const ushort* s) {
    uint4 v;
    v.x = (unsigned)s[0] | ((unsigned)s[1] << 16);
    v.y = (unsigned)s[2] | ((unsigned)s[3] << 16);
    v.z = (unsigned)s[4] | ((unsigned)s[5] << 16);
    v.w = (unsigned)s[6] | ((unsigned)s[7] << 16);
    return v;
}

// B tile-major slot (layout produced by bconv_tiles). Fragments stay
// 16B-contiguous; a wave's 64 fragment loads for one ni span 1 KB.
__device__ __forceinline__ int slotOf(int n, int lq) {
    return n * 4 + ((lq + (n >> 1)) & 3);
}

// ---------------------------------------------------------------------------
// Kernel 0: W [2048][128] fp32 -> Bt tile-major bf16 hi/lo:
// Bt[kt][part][slot][8 ushorts], kt=k/32, slot=slotOf(n,lq), elems k=lq*8+j.
// 1 MB per weight matrix. One block per kt.
// ---------------------------------------------------------------------------
__global__ __launch_bounds__(256) void bconv_tiles(
    const float* __restrict__ W, ushort* __restrict__ Bt)
{
    const int kt = blockIdx.x;       // 0..63
    const int t = threadIdx.x;
    const int n = t & 127;
    const int lq0 = (t >> 7) * 2;    // 0 or 2
    #pragma unroll
    for (int e = 0; e < 2; ++e) {
        int lq = lq0 + e;
        ushort h[8], l[8];
        #pragma unroll
        for (int j = 0; j < 8; ++j) {
            float x = W[(size_t)(kt * 32 + lq * 8 + j) * ND + n];  // coalesced
            split2(x, h[j], l[j]);
        }
        int slot = slotOf(n, lq);
        *(uint4*)&Bt[((size_t)(kt * 2 + 0) * 512 + slot) * 8] = pack8(h);
        *(uint4*)&Bt[((size_t)(kt * 2 + 1) * 512 + slot) * 8] = pack8(l);
    }
}

// ---------------------------------------------------------------------------
// Shared GEMM step — R17 issue order: split2(A(k)) [waits vmcnt(16), A is
// oldest], then A(k+1) load FIRST, then B(k+1) loads, then 24 MFMAs on B(k)
// [waits vmcnt(18) — B(k) drained, next step's 18 stay in flight].
// 2-deep B register double buffer, barrier-free; per-wave 16x128 strip.
// ---------------------------------------------------------------------------
#define QSTEP(BHC, BLC, BHN, BLN, KT)                                         \
    {                                                                         \
        short8 ah, al;                                                        \
        {                                                                     \
            S8U H, L;                                                         \
            float xs[8] = {fa0.x, fa0.y, fa0.z, fa0.w,                        \
                           fa1.x, fa1.y, fa1.z, fa1.w};                       \
            _Pragma("unroll")                                                 \
            for (int j = 0; j < 8; ++j) split2(xs[j], H.u[j], L.u[j]);        \
            ah = H.v; al = L.v;                                               \
        }                                                                     \
        const int ktn = ((KT) + 1 < KITER) ? (KT) + 1 : (KT);                 \
        fa0 = *(const float4*)(arow + ktn * 32);        /* A BEFORE B (R17) */\
        fa1 = *(const float4*)(arow + ktn * 32 + 4);                          \
        const ushort* gbn = Bt + (size_t)(kt0 + ktn) * 8192;                  \
        _Pragma("unroll")                                                     \
        for (int ni = 0; ni < 8; ++ni) {                                      \
            BHN[ni] = *(const short8*)(gbn + boff[ni]);                       \
            BLN[ni] = *(const short8*)(gbn + 4096 + boff[ni]);                \
        }                                                                     \
        _Pragma("unroll")                                                     \
        for (int ni = 0; ni < 8; ++ni) {                                      \
            acc[ni] = __builtin_amdgcn_mfma_f32_16x16x32_bf16(ah, BHC[ni], acc[ni], 0, 0, 0); \
            acc[ni] = __builtin_amdgcn_mfma_f32_16x16x32_bf16(ah, BLC[ni], acc[ni], 0, 0, 0); \
            acc[ni] = __builtin_amdgcn_mfma_f32_16x16x32_bf16(al, BHC[ni], acc[ni], 0, 0, 0); \
        }                                                                     \
    }

// ---------------------------------------------------------------------------
// Kernel 1: q = index @ Wq. v5 structure (wave=16x128, M-tile 64, grid
// (256, QSPLIT=2)=512 blocks) with R17 A-before-B issue order (prologue too).
// Partials q1/q2 non-atomic.
// ---------------------------------------------------------------------------
#define QSPLIT 2
__global__ __launch_bounds__(256) void qgemm_v11(
    const float* __restrict__ A, const ushort* __restrict__ Bt,
    float* __restrict__ q1, float* __restrict__ q2)
{
    const int tid = threadIdx.x;
    const int w = tid >> 6, lane = tid & 63;
    const int lrow = lane & 15, lq = lane >> 4;
    const int m0 = blockIdx.x * 64;
    const int KITER = (NC / QSPLIT) / 32;                 // 32
    const int kt0 = blockIdx.y * KITER;
    const int kb = blockIdx.y * (NC / QSPLIT);

    const float* arow = A + (size_t)(m0 + w * 16 + lrow) * NC + kb + lq * 8;

    int boff[8];
    #pragma unroll
    for (int ni = 0; ni < 8; ++ni)
        boff[ni] = slotOf(ni * 16 + lrow, lq) * 8;

    f32x4 acc[8];
    #pragma unroll
    for (int i = 0; i < 8; ++i) acc[i] = (f32x4){0.f, 0.f, 0.f, 0.f};

    // prologue: A(0) FIRST, then B(0) into set A (R17 order)
    float4 fa0 = *(const float4*)(arow + 0);
    float4 fa1 = *(const float4*)(arow + 4);
    short8 bhA[8], blA[8], bhB[8], blB[8];
    {
        const ushort* gb = Bt + (size_t)kt0 * 8192;   // 2*512*8 ushorts per kt
        #pragma unroll
        for (int ni = 0; ni < 8; ++ni) {
            bhA[ni] = *(const short8*)(gb + boff[ni]);
            blA[ni] = *(const short8*)(gb + 4096 + boff[ni]);
        }
    }

    for (int kt = 0; kt < KITER; kt += 2) {
        QSTEP(bhA, blA, bhB, blB, kt);
        QSTEP(bhB, blB, bhA, blA, kt + 1);
    }

    float* __restrict__ qd = blockIdx.y ? q2 : q1;
    // C/D layout: col = lane&15 (lrow), row = lq*4 + r
    #pragma unroll
    for (int ni = 0; ni < 8; ++ni) {
        const int col = ni * 16 + lrow;
        #pragma unroll
        for (int r = 0; r < 4; ++r) {
            const int grow = m0 + w * 16 + lq * 4 + r;
            qd[(size_t)grow * ND + col] = acc[ni][r];
        }
    }
}

// ---------------------------------------------------------------------------
// Kernel 1b: gathered K/V projection — same structure + R17 order via shared
// macro. grid (26, KVSPLIT=8, 2) = 416 blocks; small atomic epilogue
// (~3.4M atomics ~ 109 MB RMW — tolerated, partial buffers don't fit ws).
// ---------------------------------------------------------------------------
#define KVSPLIT 8
__global__ __launch_bounds__(256) void kvgemm_v11(
    const float* __restrict__ X, const ushort* __restrict__ Bkt,
    const ushort* __restrict__ Bvt, const int* __restrict__ topi,
    float* __restrict__ ktop, float* __restrict__ vtop)
{
    const int tid = threadIdx.x;
    const int w = tid >> 6, lane = tid & 63;
    const int lrow = lane & 15, lq = lane >> 4;
    const int m0 = blockIdx.x * 64;
    const int KITER = (NC / KVSPLIT) / 32;                // 8
    const int kt0 = blockIdx.y * KITER;
    const int kb = blockIdx.y * (NC / KVSPLIT);
    const ushort* __restrict__ Bt = blockIdx.z ? Bvt : Bkt;

    const int gi = m0 + w * 16 + lrow;
    const int giC = gi < NM ? gi : NM - 1;
    const int b = giC / NK, ii = giC % NK;
    const int src = topi[b * KPAD + ii];
    const float* arow = X + ((size_t)b * NT + src) * NC + kb + lq * 8;

    int boff[8];
    #pragma unroll
    for (int ni = 0; ni < 8; ++ni)
        boff[ni] = slotOf(ni * 16 + lrow, lq) * 8;

    f32x4 acc[8];
    #pragma unroll
    for (int i = 0; i < 8; ++i) acc[i] = (f32x4){0.f, 0.f, 0.f, 0.f};

    float4 fa0 = *(const float4*)(arow + 0);
    float4 fa1 = *(const float4*)(arow + 4);
    short8 bhA[8], blA[8], bhB[8], blB[8];
    {
        const ushort* gb = Bt + (size_t)kt0 * 8192;
        #pragma unroll
        for (int ni = 0; ni < 8; ++ni) {
            bhA[ni] = *(const short8*)(gb + boff[ni]);
            blA[ni] = *(const short8*)(gb + 4096 + boff[ni]);
        }
    }

    for (int kt = 0; kt < KITER; kt += 2) {
        QSTEP(bhA, blA, bhB, blB, kt);
        QSTEP(bhB, blB, bhA, blA, kt + 1);
    }

    float* __restrict__ dst = blockIdx.z ? vtop : ktop;
    #pragma unroll
    for (int ni = 0; ni < 8; ++ni) {
        const int col = ni * 16 + lrow;
        #pragma unroll
        for (int r = 0; r < 4; ++r) {
            const int grow = m0 + w * 16 + lq * 4 + r;
            if (grow < NM)
                atomicAdd(&dst[(size_t)grow * ND + col], acc[ni][r]);
        }
    }
}

// ---------------------------------------------------------------------------
// Kernel 2: q = q1 + q2 (in-place into q1) + q_norms. One wave per row.
// ---------------------------------------------------------------------------
__global__ __launch_bounds__(256) void qnorm_kernel(
    float* __restrict__ q1, const float* __restrict__ q2, float* __restrict__ qn)
{
    const int wv = (blockIdx.x * 256 + threadIdx.x) >> 6;
    const int lane = threadIdx.x & 63;
    float* r1 = q1 + (size_t)wv * ND;
    const float* r2 = q2 + (size_t)wv * ND;
    float a = r1[lane] + r2[lane];
    float b = r1[lane + 64] + r2[lane + 64];
    r1[lane] = a;
    r1[lane + 64] = b;
    float s = a * a + b * b;
    #pragma unroll
    for (int off = 32; off > 0; off >>= 1) s += __shfl_xor(s, off);
    if (lane == 0) qn[wv] = sqrtf(s);
}

// ---------------------------------------------------------------------------
// Kernel 3: exact top-k by rank counting (jax.lax.top_k tie rules).
// ---------------------------------------------------------------------------
__global__ __launch_bounds__(256) void topk_kernel(
    const float* __restrict__ qn, int* __restrict__ topi, int* __restrict__ cnt)
{
    __shared__ int rs[4][64];
    const int b = blockIdx.y;
    const int is = threadIdx.x & 63;
    const int i = blockIdx.x * 64 + is;
    const int chunk = threadIdx.x >> 6;
    const float vi = qn[(size_t)b * NT + i];
    const float4* qv = (const float4*)(qn + (size_t)b * NT + chunk * 1024);
    int rank = 0;
    #pragma unroll 4
    for (int j4 = 0; j4 < 256; ++j4) {
        float4 v = qv[j4];
        int j = chunk * 1024 + j4 * 4;
        rank += (v.x > vi || (v.x == vi && (j + 0) < i)) ? 1 : 0;
        rank += (v.y > vi || (v.y == vi && (j + 1) < i)) ? 1 : 0;
        rank += (v.z > vi || (v.z == vi && (j + 2) < i)) ? 1 : 0;
        rank += (v.w > vi || (v.w == vi && (j + 3) < i)) ? 1 : 0;
    }
    rs[chunk][is] = rank;
    __syncthreads();
    if (threadIdx.x < 64) {
        int rk = rs[0][threadIdx.x] + rs[1][threadIdx.x] + rs[2][threadIdx.x] + rs[3][threadIdx.x];
        if (rk < NK) {
            int p = atomicAdd(&cnt[b], 1);
            topi[b * KPAD + p] = blockIdx.x * 64 + threadIdx.x;
        }
    }
}

// ---------------------------------------------------------------------------
// Kernel 5: per (batch, top-k row): scores -> softmax -> PV -> scatter.
// ---------------------------------------------------------------------------
__global__ __launch_bounds__(256) void attn_kernel(
    const float* __restrict__ q, const float* __restrict__ ktop,
    const float* __restrict__ vtop, const int* __restrict__ topi,
    float* __restrict__ out)
{
    __shared__ float qs[ND];
    __shared__ float ss[KPAD];
    __shared__ float red[256];
    __shared__ float pv[2][ND];
    const int bi = blockIdx.x;
    const int b = bi / NK, i = bi % NK;
    const int t = threadIdx.x;
    const int row = topi[b * KPAD + i];
    if (t < ND) qs[t] = q[((size_t)b * NT + row) * ND + t];
    __syncthreads();

    const float scale = 0.08838834764831844f;   // 1/sqrt(128)
    float mymax = -1e30f;
    #pragma unroll
    for (int rep = 0; rep < 2; ++rep) {
        int j = t + rep * 256;
        if (j < NK) {
            const float4* kr = (const float4*)(ktop + ((size_t)b * NK + j) * ND);
            const float4* q4 = (const float4*)qs;
            float s = 0.f;
            #pragma unroll
            for (int dd = 0; dd < 32; ++dd) {
                float4 a = q4[dd], kv = kr[dd];
                s += a.x * kv.x + a.y * kv.y + a.z * kv.z + a.w * kv.w;
            }
            s *= scale;
            ss[j] = s;
            mymax = fmaxf(mymax, s);
        }
    }
    red[t] = mymax;
    __syncthreads();
    for (int off = 128; off > 0; off >>= 1) {
        if (t < off) red[t] = fmaxf(red[t], red[t + off]);
        __syncthreads();
    }
    const float mx = red[0];
    __syncthreads();

    float mysum = 0.f;
    #pragma unroll
    for (int rep = 0; rep < 2; ++rep) {
        int j = t + rep * 256;
        if (j < NK) {
            float p = __expf(ss[j] - mx);
            ss[j] = p;
            mysum += p;
        }
    }
    red[t] = mysum;
    __syncthreads();
    for (int off = 128; off > 0; off >>= 1) {
        if (t < off) red[t] += red[t + off];
        __syncthreads();
    }
    const float inv = 1.f / red[0];

    const int col = t & (ND - 1), half = t >> 7;
    float o = 0.f;
    #pragma unroll 4
    for (int j = half; j < NK; j += 2)
        o = fmaf(ss[j], vtop[((size_t)b * NK + j) * ND + col], o);
    pv[half][col] = o;
    __syncthreads();
    if (t < ND)
        out[((size_t)b * NT + row) * ND + t] = (pv[0][t] + pv[1][t]) * inv;
}

// ---------------------------------------------------------------------------
extern "C" void kernel_launch(void* const* d_in, const int* in_sizes, int n_in,
                              void* d_out, int out_size, void* d_ws, size_t ws_size,
                              hipStream_t stream)
{
    const float* index = (const float*)d_in[0];
    const float* Wq = (const float*)d_in[1];
    const float* Wk = (const float*)d_in[2];
    const float* Wv = (const float*)d_in[3];
    float* out = (float*)d_out;

    // ws: 10,137,856 B proven footprint.
    char* ws = (char*)d_ws;
    float*  q1   = (float*)(ws);                       // 8,388,608
    float*  qn   = (float*)(ws + 8388608);             //    65,536
    int*    topi = (int*)  (ws + 8454144);             //     8,192
    int*    cnt  = (int*)  (ws + 8462336);             //       256
    ushort* Bqt  = (ushort*)(ws + 8462592);            // 1,048,576 (phase 1)
    float*  ktop = (float*)(ws + 8462592);             //   837,632 (phase 2)
    float*  vtop = (float*)(ws + 9300224);             //   837,632 (phase 2)

    // d_out scratch: q2 partial (phase A), then Bkt/Bvt (phase B), then output.
    float*  q2  = (float*)d_out;
    ushort* Bkt = (ushort*)d_out;                      // 1,048,576
    ushort* Bvt = (ushort*)((char*)d_out + 1048576);   // 1,048,576

    hipMemsetAsync(cnt, 0, NB * sizeof(int), stream);

    bconv_tiles<<<dim3(64), dim3(256), 0, stream>>>(Wq, Bqt);
    qgemm_v11<<<dim3(NB * NT / 64, QSPLIT), dim3(256), 0, stream>>>(index, Bqt, q1, q2);
    qnorm_kernel<<<dim3(NB * NT / 4), dim3(256), 0, stream>>>(q1, q2, qn);
    topk_kernel<<<dim3(NT / 64, NB), dim3(256), 0, stream>>>(qn, topi, cnt);
    bconv_tiles<<<dim3(64), dim3(256), 0, stream>>>(Wk, Bkt);
    bconv_tiles<<<dim3(64), dim3(256), 0, stream>>>(Wv, Bvt);
    hipMemsetAsync(ktop, 0, 2 * 837632, stream);   // zero ktop+vtop (atomic accum)
    kvgemm_v11<<<dim3((NM + 63) / 64, KVSPLIT, 2), dim3(256), 0, stream>>>(
        index, Bkt, Bvt, topi, ktop, vtop);
    hipMemsetAsync(d_out, 0, (size_t)out_size * sizeof(float), stream);
    attn_kernel<<<dim3(NM), dim3(256), 0, stream>>>(q1, ktop, vtop, topi, out);
}